// Round 1
// baseline (254.791 us; speedup 1.0000x reference)
//
#include <hip/hip_runtime.h>
#include <math.h>

#define NB 128
#define NS 256
#define NH 768
#define NL 24
#define ASTR 68   // A-tile LDS stride (words): 68%32=4 -> 2-way banks, 16B-aligned rows
#define E_BYTES (NB*NS*NL*4)   // 3,145,728 B

// Fused kernel. Blocks [0,128): Viterbi consumers (dispatched first, spin on
// per-batch ready counter). Blocks [128,1152): emission producers (one 32-token
// tile each), release-signal ready[b] when their tile of E is globally visible.
// LDS: union of emis scratch (25.6 KB) and viterbi scratch (33.2 KB) -> 4 blocks/CU.
__global__ __launch_bounds__(256) void ner_fused(
    const float* __restrict__ tf, const int* __restrict__ tlm,
    const float* __restrict__ W, const float* __restrict__ bias,
    const float* __restrict__ trans, const float* __restrict__ st,
    const float* __restrict__ en, float* __restrict__ E,
    int* __restrict__ ready, int* __restrict__ out)
{
    __shared__ __align__(16) unsigned char smem[33184];
    const int tid = threadIdx.x;

    if (blockIdx.x >= NB) {
        // ---------------- emission producer: tile GEMM + sigmoid ----------------
        const int bid  = blockIdx.x - NB;
        const int b    = bid >> 3;
        const int tile = (bid & 7) << 5;              // token base of this tile
        if (tlm[b*NS + tile] == 0) {                  // prefix mask: whole tile invalid
            if (tid == 0)
                __hip_atomic_fetch_add(&ready[b], 1, __ATOMIC_RELEASE, __HIP_MEMORY_SCOPE_AGENT);
            return;
        }

        float* lds = (float*)smem;
        float* As = lds;                              // [32][ASTR]
        float* Ws = lds + 32*ASTR;                    // [64][24]
        float* Pr = lds;                              // [8][32][25] reduction (after K-loop)

        const int tok  = tid & 15;
        const int ksub = tid >> 4;                    // 0..15
        const int kk   = ksub << 2;                   // k base within 64-chunk
        const int rot  = ksub & 3;                    // bank-phase rotation

        float acc0[NL], acc1[NL];
        #pragma unroll
        for (int l = 0; l < NL; ++l) { acc0[l] = 0.f; acc1[l] = 0.f; }

        const float* tfb = tf + (size_t)(b*NS)*NH;

        for (int kc0 = 0; kc0 < NH; kc0 += 64) {
            // ---- stage A chunk [32 tok][64 k]: 512 float4, 2/thread, coalesced ----
            #pragma unroll
            for (int i = 0; i < 2; ++i) {
                int idx  = tid + (i << 8);
                int row  = idx >> 4;                  // token row 0..31
                int c4   = idx & 15;                  // float4 col 0..15
                int trow = tile + row + 1;            // feature row = token+1
                if (trow > 255) trow = 255;           // clamp (row invalid anyway)
                float4 v = *(const float4*)(tfb + (size_t)trow*NH + kc0 + (c4 << 2));
                float* dst = As + row*ASTR + (c4 << 2);
                dst[0] = v.x; dst[1] = v.y; dst[2] = v.z; dst[3] = v.w;
            }
            // ---- stage W chunk [64 k][24 l]: 384 contiguous float4 ----
            {
                const float4* wsrc = (const float4*)(W + (size_t)kc0*NL);
                float4* wdst = (float4*)Ws;
                for (int i = tid; i < 384; i += 256) wdst[i] = wsrc[i];
            }
            __syncthreads();

            const float* A0 = As + tok*ASTR + kk;
            const float* A1 = A0 + 16*ASTR;
            const float* Wr = Ws + kk*NL;
            #pragma unroll
            for (int s = 0; s < 4; ++s) {
                const int j = (s + rot) & 3;          // rotated row order (bank phase)
                float a0 = A0[j];
                float a1 = A1[j];
                const float4* w4 = (const float4*)(Wr + j*NL);
                float wv[NL];
                #pragma unroll
                for (int i = 0; i < 6; ++i) {         // 6 broadcast ds_read_b128
                    float4 w = w4[i];
                    wv[4*i+0] = w.x; wv[4*i+1] = w.y; wv[4*i+2] = w.z; wv[4*i+3] = w.w;
                }
                #pragma unroll
                for (int l = 0; l < NL; ++l) {
                    acc0[l] = fmaf(a0, wv[l], acc0[l]);
                    acc1[l] = fmaf(a1, wv[l], acc1[l]);
                }
            }
            __syncthreads();
        }

        // ---- fold 16 ksub partials -> 8, then final (fixed order: deterministic) ----
        if (ksub >= 8) {
            float* p = Pr + ((ksub-8)*32 + tok)*25;
            float* q = p + 16*25;
            #pragma unroll
            for (int l = 0; l < NL; ++l) { p[l] = acc0[l]; q[l] = acc1[l]; }
        }
        __syncthreads();
        if (ksub < 8) {
            const float* p = Pr + (ksub*32 + tok)*25;
            const float* q = p + 16*25;
            #pragma unroll
            for (int l = 0; l < NL; ++l) { acc0[l] += p[l]; acc1[l] += q[l]; }
        }
        __syncthreads();
        if (ksub < 8) {
            float* p = Pr + (ksub*32 + tok)*25;
            float* q = p + 16*25;
            #pragma unroll
            for (int l = 0; l < NL; ++l) { p[l] = acc0[l]; q[l] = acc1[l]; }
        }
        __syncthreads();

        const int* tm = tlm + b*NS + tile;
        float* Eb = E + (size_t)(b*NS + tile)*NL;
        #pragma unroll
        for (int i = 0; i < 3; ++i) {
            int o = tid + (i << 8);                   // 0..767 (32 tok x 24 lab)
            int t = o / NL, l = o % NL;
            if (tm[t]) {
                float s = 0.f;
                #pragma unroll
                for (int ks = 0; ks < 8; ++ks)        // fixed ascending order
                    s += Pr[(ks*32 + t)*25 + l];
                float x = s + bias[l];
                Eb[t*NL + l] = 1.0f/(1.0f + expf(-x));
            }
        }
        __syncthreads();                              // all stores issued & drained
        if (tid == 0)
            __hip_atomic_fetch_add(&ready[b], 1, __ATOMIC_RELEASE, __HIP_MEMORY_SCOPE_AGENT);
        return;
    }

    // ---------------- Viterbi consumer: one block per batch ----------------
    const int b  = blockIdx.x;
    const int bS = b*NS;

    float* scl = (float*)smem;                        // [NS*NL] per-step score vectors
    float* Tt  = scl + NS*NL;                         // [NL*NL] Tt[c*24+p] = T[p][c]
    float* fin = Tt + NL*NL;                          // [NL]
    int*   chosen = (int*)(fin + NL);                 // [12]
    int*   misc   = chosen + 12;                      // [0]=n, [1]=last_tag
    unsigned char* tr_s = (unsigned char*)(misc + 2); // [NL][NS] trace

    const int c = tid % 24;                           // tag lane (wave 0 use)
    float Tc[24];

    // prep that doesn't need E runs concurrently with the spin (tid 224 spins)
    if (tid < 64) {
        #pragma unroll
        for (int p = 0; p < 24; ++p) Tc[p] = trans[p*NL + c];
        // n = lengths[b]-2 (contiguous prefix mask)
        int a = tlm[bS+tid] + tlm[bS+tid+64] + tlm[bS+tid+128] + tlm[bS+tid+192];
        #pragma unroll
        for (int off = 32; off > 0; off >>= 1) a += __shfl_down(a, off, 64);
        if (tid == 0) misc[0] = a;
    }
    if (tid >= 64 && tid < 192) {
        for (int i = tid - 64; i < NL*NL; i += 128) {
            int cc = i / NL, p = i % NL;
            Tt[i] = trans[p*NL + cc];
        }
    }
    if (tid == 224) {                                 // spin until all 8 tiles published
        while (__hip_atomic_load(&ready[b], __ATOMIC_RELAXED, __HIP_MEMORY_SCOPE_AGENT) < 8)
            __builtin_amdgcn_s_sleep(8);
        __threadfence();                              // agent acquire: inv L1/L2
    }
    __syncthreads();
    const int n = misc[0];                            // n >= 1 always

    // ---- forward: wave 0, lane = curr tag; E read direct from global,
    //      8-deep double-buffered register prefetch hides HBM/L3 latency ----
    if (tid < 64) {
        const float* Eg = E + (size_t)bS*NL + c;      // row stride NL

        auto rl = [](float v, int p) {
            return __int_as_float(__builtin_amdgcn_readlane(__float_as_int(v), p));
        };

        float sv = st[c] + Eg[0];
        scl[c] = sv;
        float scr[24];
        #pragma unroll
        for (int p = 0; p < 24; ++p) scr[p] = rl(sv, p);

        auto step = [&](int t, float em) {
            float cand[24];
            #pragma unroll
            for (int p = 0; p < 24; ++p) cand[p] = scr[p] + Tc[p];
            float m0 = fmaxf(fmaxf(cand[0],  cand[1]),  cand[2]);
            float m1 = fmaxf(fmaxf(cand[3],  cand[4]),  cand[5]);
            float m2 = fmaxf(fmaxf(cand[6],  cand[7]),  cand[8]);
            float m3 = fmaxf(fmaxf(cand[9],  cand[10]), cand[11]);
            float m4 = fmaxf(fmaxf(cand[12], cand[13]), cand[14]);
            float m5 = fmaxf(fmaxf(cand[15], cand[16]), cand[17]);
            float m6 = fmaxf(fmaxf(cand[18], cand[19]), cand[20]);
            float m7 = fmaxf(fmaxf(cand[21], cand[22]), cand[23]);
            float q0 = fmaxf(fmaxf(m0, m1), m2);
            float q1 = fmaxf(fmaxf(m3, m4), m5);
            float q2 = fmaxf(m6, m7);
            float best = fmaxf(fmaxf(q0, q1), q2);
            sv = best + em;
            scl[t*NL + c] = sv;                       // off critical path
            #pragma unroll
            for (int p = 0; p < 24; ++p) scr[p] = rl(sv, p);
        };

        float emA[8], emB[8];
        #pragma unroll
        for (int j = 0; j < 8; ++j) emA[j] = Eg[(size_t)(1+j)*NL];  // rows 1..8

        int t = 1;
        for (; t + 8 <= n; t += 8) {
            // prefetch next group (rows t+8..t+15, clamped; garbage rows unused)
            #pragma unroll
            for (int j = 0; j < 8; ++j) {
                int r = t + 8 + j; if (r > 255) r = 255;
                emB[j] = Eg[(size_t)r*NL];
            }
            #pragma unroll
            for (int j = 0; j < 8; ++j) step(t + j, emA[j]);
            #pragma unroll
            for (int j = 0; j < 8; ++j) emA[j] = emB[j];
        }
        {   // tail: last prefetch group already holds rows t..t+7 (static index)
            const int t0 = t;
            #pragma unroll
            for (int j = 0; j < 8; ++j)
                if (t0 + j < n) step(t0 + j, emA[j]);
        }
        fin[c] = sv + en[c];
    }
    __syncthreads();

    if (tid == 0) {   // argmax(final), first-max tie rule like jnp.argmax
        float bv = fin[0]; int bt = 0;
        #pragma unroll
        for (int cc = 1; cc < 24; ++cc) { if (fin[cc] > bv) { bv = fin[cc]; bt = cc; } }
        misc[1] = bt;
    }
    __syncthreads();
    const int ltag = misc[1];

    // ---- backtrack: 10 windows x 24 hypotheses, recompute backpointers ----
    const int K = (n > 1) ? (n - 1 + 9) / 10 : 1;
    if (n > 1 && tid < 240) {
        const int w = tid / 24 + 1, h = tid % 24;
        int tlo = (w-1)*K; if (tlo > n-1) tlo = n-1;
        int thi = w*K;     if (thi > n-1) thi = n-1;
        int cur = h;
        for (int t = thi; t > tlo; --t) {
            const float4* sp = (const float4*)(scl + (t-1)*NL);
            const float4* up = (const float4*)(Tt  + cur*NL);
            float cand[24];
            #pragma unroll
            for (int i = 0; i < 6; ++i) {
                float4 s = sp[i], u = up[i];
                cand[4*i+0] = s.x + u.x;     // bitwise-identical to forward cand
                cand[4*i+1] = s.y + u.y;
                cand[4*i+2] = s.z + u.z;
                cand[4*i+3] = s.w + u.w;
            }
            float best = cand[0]; int arg = 0;
            #pragma unroll
            for (int p = 1; p < 24; ++p) { if (cand[p] > best) { best = cand[p]; arg = p; } }
            tr_s[h*NS + (t-1)] = (unsigned char)arg;
            cur = arg;
        }
    }
    __syncthreads();

    if (tid == 0) {   // stitch windows
        int cur = ltag;
        for (int w = 10; w >= 1; --w) {
            chosen[w] = cur;
            int tlo = (w-1)*K; if (tlo > n-1) tlo = n-1;
            int thi = w*K;     if (thi > n-1) thi = n-1;
            if (thi > tlo) cur = tr_s[cur*NS + tlo];
        }
    }
    __syncthreads();

    {   // emit path: t >= n-1 -> last_tag (identity backpointers on padding)
        const int t = tid;
        int tag;
        if (t >= n-1) tag = ltag;
        else { int w = t / K + 1; tag = tr_s[chosen[w]*NS + t]; }
        out[bS + t] = tag;
    }
}

extern "C" void kernel_launch(void* const* d_in, const int* in_sizes, int n_in,
                              void* d_out, int out_size, void* d_ws, size_t ws_size,
                              hipStream_t stream) {
    const float* tf    = (const float*)d_in[0];
    const int*   tlm   = (const int*)  d_in[2];   // true_label_mask
    const float* W     = (const float*)d_in[3];
    const float* bias  = (const float*)d_in[4];
    const float* trans = (const float*)d_in[5];
    const float* st    = (const float*)d_in[6];
    const float* en    = (const float*)d_in[7];
    float* E     = (float*)d_ws;                            // [128,256,24] fp32
    int*   ready = (int*)((char*)d_ws + E_BYTES);           // [128] per-batch counters

    hipMemsetAsync(ready, 0, NB*sizeof(int), stream);       // ws is re-poisoned per iter
    ner_fused<<<dim3(NB + NB*8), dim3(256), 0, stream>>>(
        tf, tlm, W, bias, trans, st, en, E, ready, (int*)d_out);
}

// Round 2
// 209.432 us; speedup vs baseline: 1.2166x; 1.2166x over previous
//
#include <hip/hip_runtime.h>
#include <math.h>

#define NB 128
#define NS 256
#define NH 768
#define NL 24
#define ASTR 68   // A-tile LDS stride (words): 68%32=4 -> 2-way banks, 16B-aligned rows

// ---------------- Kernel A: emissions = sigmoid(tf[b,t+1,:] @ W + b) for t < n_b ----
// (unchanged from verified round-0 version)
__global__ __launch_bounds__(256) void ner_emis(
    const float* __restrict__ tf, const int* __restrict__ tlm,
    const float* __restrict__ W, const float* __restrict__ bias,
    float* __restrict__ E)
{
    const int b    = blockIdx.x >> 3;
    const int tile = (blockIdx.x & 7) << 5;         // token base of this tile
    const int tid  = threadIdx.x;
    if (tlm[b*NS + tile] == 0) return;              // prefix mask: whole tile invalid

    __shared__ float lds[8*32*25];                  // 25.6 KB union
    float* As = lds;                                // [32][ASTR] = 2176 words (8.5 KB)
    float* Ws = lds + 32*ASTR;                      // [64][24]   = 1536 words (6 KB)
    float* Pr = lds;                                // [8][32][25] reduction (after K-loop)

    const int tok  = tid & 15;
    const int ksub = tid >> 4;                      // 0..15
    const int kk   = ksub << 2;                     // k base within 64-chunk
    const int rot  = ksub & 3;                      // bank-phase rotation

    float acc0[NL], acc1[NL];
    #pragma unroll
    for (int l = 0; l < NL; ++l) { acc0[l] = 0.f; acc1[l] = 0.f; }

    const float* tfb = tf + (size_t)(b*NS)*NH;

    for (int kc0 = 0; kc0 < NH; kc0 += 64) {
        // ---- stage A chunk [32 tok][64 k]: 512 float4, 2/thread, coalesced ----
        #pragma unroll
        for (int i = 0; i < 2; ++i) {
            int idx  = tid + (i << 8);
            int row  = idx >> 4;                    // token row 0..31
            int c4   = idx & 15;                    // float4 col 0..15
            int trow = tile + row + 1;              // feature row = token+1
            if (trow > 255) trow = 255;             // clamp (row invalid anyway)
            float4 v = *(const float4*)(tfb + (size_t)trow*NH + kc0 + (c4 << 2));
            float* dst = As + row*ASTR + (c4 << 2);
            dst[0] = v.x; dst[1] = v.y; dst[2] = v.z; dst[3] = v.w;
        }
        // ---- stage W chunk [64 k][24 l]: 384 contiguous float4 ----
        {
            const float4* wsrc = (const float4*)(W + (size_t)kc0*NL);
            float4* wdst = (float4*)Ws;
            for (int i = tid; i < 384; i += 256) wdst[i] = wsrc[i];
        }
        __syncthreads();

        const float* A0 = As + tok*ASTR + kk;
        const float* A1 = A0 + 16*ASTR;
        const float* Wr = Ws + kk*NL;
        #pragma unroll
        for (int s = 0; s < 4; ++s) {
            const int j = (s + rot) & 3;            // rotated row order (bank phase)
            float a0 = A0[j];
            float a1 = A1[j];
            const float4* w4 = (const float4*)(Wr + j*NL);
            float wv[NL];
            #pragma unroll
            for (int i = 0; i < 6; ++i) {           // 6 broadcast ds_read_b128
                float4 w = w4[i];
                wv[4*i+0] = w.x; wv[4*i+1] = w.y; wv[4*i+2] = w.z; wv[4*i+3] = w.w;
            }
            #pragma unroll
            for (int l = 0; l < NL; ++l) {
                acc0[l] = fmaf(a0, wv[l], acc0[l]);
                acc1[l] = fmaf(a1, wv[l], acc1[l]);
            }
        }
        __syncthreads();
    }

    // ---- fold 16 ksub partials -> 8 (ksub>=8 publish, ksub<8 add), then final ----
    if (ksub >= 8) {
        float* p = Pr + ((ksub-8)*32 + tok)*25;
        float* q = p + 16*25;
        #pragma unroll
        for (int l = 0; l < NL; ++l) { p[l] = acc0[l]; q[l] = acc1[l]; }
    }
    __syncthreads();
    if (ksub < 8) {
        const float* p = Pr + (ksub*32 + tok)*25;
        const float* q = p + 16*25;
        #pragma unroll
        for (int l = 0; l < NL; ++l) { acc0[l] += p[l]; acc1[l] += q[l]; }
    }
    __syncthreads();
    if (ksub < 8) {
        float* p = Pr + (ksub*32 + tok)*25;
        float* q = p + 16*25;
        #pragma unroll
        for (int l = 0; l < NL; ++l) { p[l] = acc0[l]; q[l] = acc1[l]; }
    }
    __syncthreads();

    const int* tm = tlm + b*NS + tile;
    float* Eb = E + (size_t)(b*NS + tile)*NL;
    #pragma unroll
    for (int i = 0; i < 3; ++i) {
        int o = tid + (i << 8);                     // 0..767 (32 tok x 24 lab)
        int t = o / NL, l = o % NL;
        if (tm[t]) {
            float s = 0.f;
            #pragma unroll
            for (int ks = 0; ks < 8; ++ks)          // fixed ascending order: deterministic
                s += Pr[(ks*32 + t)*25 + l];
            float x = s + bias[l];
            Eb[t*NL + l] = 1.0f/(1.0f + expf(-x));
        }
    }
}

// ---------------- Kernel B: masked Viterbi decode, one block (256 thr) per batch ----
// Forward-loop broadcast changed: the per-step score vector is re-read from scl
// (which the step writes anyway for the backtrack) as 6 wave-uniform ds_read_b128
// (same-address broadcast, conflict-free) instead of 24 v_readlane VALU->SGPR ops.
__global__ __launch_bounds__(256) void ner_viterbi(
    const float* __restrict__ E, const int* __restrict__ tlm,
    const float* __restrict__ trans, const float* __restrict__ st,
    const float* __restrict__ en, int* __restrict__ out)
{
    const int tid = threadIdx.x;
    const int b   = blockIdx.x;
    const int bS  = b*NS;

    __shared__ float Esh[NS*NL];            // preloaded emissions (24.5 KB)
    __shared__ float scl[NS*NL];            // per-step score vectors (24.5 KB)
    __shared__ float Tt[NL*NL];             // Tt[c*24+p] = T[p][c]
    __shared__ float fin[NL];
    __shared__ unsigned char tr_s[NL][NS];  // trace[hypothesis][t]
    __shared__ int chosen[12];
    __shared__ int nsh, ltag;

    {
        const float4* src = (const float4*)(E + (size_t)bS*NL);
        float4* dst = (float4*)Esh;
        #pragma unroll
        for (int j = 0; j < 6; ++j) dst[tid + (j << 8)] = src[tid + (j << 8)];
    }
    for (int i = tid; i < NL*NL; i += 256) {
        int c = i / NL, p = i % NL;
        Tt[i] = trans[p*NL + c];
    }
    if (tid < 64) {   // n = lengths[b]-2 (contiguous prefix mask)
        int a = tlm[bS+tid] + tlm[bS+tid+64] + tlm[bS+tid+128] + tlm[bS+tid+192];
        #pragma unroll
        for (int off = 32; off > 0; off >>= 1) a += __shfl_down(a, off, 64);
        if (tid == 0) nsh = a;
    }
    __syncthreads();
    const int n = nsh;   // n >= 1 always

    // ---- forward: lanes 0..23 of wave 0, lane = curr tag ----
    if (tid < 24) {
        const int c = tid;
        float Tc[24];
        #pragma unroll
        for (int p = 0; p < 24; ++p) Tc[p] = trans[p*NL + c];

        float sv = st[c] + Esh[c];
        scl[c] = sv;                         // score vector t=0, read back next step

        auto step = [&](int t, float em) {
            // broadcast read of previous score vector: wave-uniform address
            const float4* sp = (const float4*)(scl + (t-1)*NL);
            float cand[24];
            #pragma unroll
            for (int i = 0; i < 6; ++i) {    // 6 broadcast ds_read_b128
                float4 s = sp[i];
                cand[4*i+0] = s.x + Tc[4*i+0];   // bitwise: scr[p] + Tc[p], as before
                cand[4*i+1] = s.y + Tc[4*i+1];
                cand[4*i+2] = s.z + Tc[4*i+2];
                cand[4*i+3] = s.w + Tc[4*i+3];
            }
            float m0 = fmaxf(fmaxf(cand[0],  cand[1]),  cand[2]);
            float m1 = fmaxf(fmaxf(cand[3],  cand[4]),  cand[5]);
            float m2 = fmaxf(fmaxf(cand[6],  cand[7]),  cand[8]);
            float m3 = fmaxf(fmaxf(cand[9],  cand[10]), cand[11]);
            float m4 = fmaxf(fmaxf(cand[12], cand[13]), cand[14]);
            float m5 = fmaxf(fmaxf(cand[15], cand[16]), cand[17]);
            float m6 = fmaxf(fmaxf(cand[18], cand[19]), cand[20]);
            float m7 = fmaxf(fmaxf(cand[21], cand[22]), cand[23]);
            float q0 = fmaxf(fmaxf(m0, m1), m2);
            float q1 = fmaxf(fmaxf(m3, m4), m5);
            float q2 = fmaxf(m6, m7);
            float best = fmaxf(fmaxf(q0, q1), q2);
            sv = best + em;
            scl[t*NL + c] = sv;              // publishes broadcast for step t+1
        };

        int t = 1;
        for (; t + 8 <= n; t += 8) {
            float em[8];
            const float* eb = Esh + t*NL + c;
            #pragma unroll
            for (int j = 0; j < 8; ++j) em[j] = eb[j*NL];   // 8 indep ds_read, imm offs
            #pragma unroll
            for (int j = 0; j < 8; ++j) step(t + j, em[j]);
        }
        for (; t < n; ++t) step(t, Esh[t*NL + c]);
        fin[c] = sv + en[c];
    }
    __syncthreads();

    if (tid == 0) {   // argmax(final), first-max tie rule like jnp.argmax
        float bv = fin[0]; int bt = 0;
        #pragma unroll
        for (int cc = 1; cc < 24; ++cc) { if (fin[cc] > bv) { bv = fin[cc]; bt = cc; } }
        ltag = bt;
    }
    __syncthreads();

    // ---- backtrack: 10 windows x 24 hypotheses, recompute backpointers ----
    const int K = (n > 1) ? (n - 1 + 9) / 10 : 1;
    if (n > 1 && tid < 240) {
        const int w = tid / 24 + 1, h = tid % 24;
        int tlo = (w-1)*K; if (tlo > n-1) tlo = n-1;
        int thi = w*K;     if (thi > n-1) thi = n-1;
        int cur = h;
        for (int t = thi; t > tlo; --t) {
            const float4* sp = (const float4*)(scl + (t-1)*NL);
            const float4* up = (const float4*)(Tt  + cur*NL);
            float cand[24];
            #pragma unroll
            for (int i = 0; i < 6; ++i) {
                float4 s = sp[i], u = up[i];
                cand[4*i+0] = s.x + u.x;     // bitwise-identical to forward cand
                cand[4*i+1] = s.y + u.y;
                cand[4*i+2] = s.z + u.z;
                cand[4*i+3] = s.w + u.w;
            }
            float best = cand[0]; int arg = 0;
            #pragma unroll
            for (int p = 1; p < 24; ++p) { if (cand[p] > best) { best = cand[p]; arg = p; } }
            tr_s[h][t-1] = (unsigned char)arg;
            cur = arg;
        }
    }
    __syncthreads();

    if (tid == 0) {   // stitch windows
        int cur = ltag;
        for (int w = 10; w >= 1; --w) {
            chosen[w] = cur;
            int tlo = (w-1)*K; if (tlo > n-1) tlo = n-1;
            int thi = w*K;     if (thi > n-1) thi = n-1;
            if (thi > tlo) cur = tr_s[cur][tlo];
        }
    }
    __syncthreads();

    {   // emit path: t >= n-1 -> last_tag (identity backpointers on padding)
        const int t = tid;
        int tag;
        if (t >= n-1) tag = ltag;
        else { int w = t / K + 1; tag = tr_s[chosen[w]][t]; }
        out[bS + t] = tag;
    }
}

extern "C" void kernel_launch(void* const* d_in, const int* in_sizes, int n_in,
                              void* d_out, int out_size, void* d_ws, size_t ws_size,
                              hipStream_t stream) {
    const float* tf    = (const float*)d_in[0];
    const int*   tlm   = (const int*)  d_in[2];   // true_label_mask
    const float* W     = (const float*)d_in[3];
    const float* bias  = (const float*)d_in[4];
    const float* trans = (const float*)d_in[5];
    const float* st    = (const float*)d_in[6];
    const float* en    = (const float*)d_in[7];
    float* E = (float*)d_ws;                      // [128,256,24] fp32 = 3.1 MB

    ner_emis<<<dim3(NB*8), dim3(256), 0, stream>>>(tf, tlm, W, bias, E);
    ner_viterbi<<<dim3(NB), dim3(256), 0, stream>>>(E, tlm, trans, st, en, (int*)d_out);
}

// Round 3
// 202.106 us; speedup vs baseline: 1.2607x; 1.0362x over previous
//
#include <hip/hip_runtime.h>
#include <math.h>

#define NB 128
#define NS 256
#define NH 768
#define NL 24
#define ASTR 68   // A-tile LDS stride (words): 68%32=4 -> 2-way banks, 16B-aligned rows

// ---------------- Kernel A: emissions = sigmoid(tf[b,t+1,:] @ W + b) for t < n_b ----
// Reg-staged prefetch (T14 async-split): chunk k+1's global loads are issued before
// chunk k's compute; the vmcnt wait + ds_write land after compute, between barriers.
// Same LDS footprint and bitwise-identical arithmetic to the verified version.
__global__ __launch_bounds__(256) void ner_emis(
    const float* __restrict__ tf, const int* __restrict__ tlm,
    const float* __restrict__ W, const float* __restrict__ bias,
    float* __restrict__ E)
{
    const int b    = blockIdx.x >> 3;
    const int tile = (blockIdx.x & 7) << 5;         // token base of this tile
    const int tid  = threadIdx.x;
    if (tlm[b*NS + tile] == 0) return;              // prefix mask: whole tile invalid

    __shared__ float lds[8*32*25];                  // 25.6 KB union
    float* As = lds;                                // [32][ASTR] = 2176 words (8.5 KB)
    float* Ws = lds + 32*ASTR;                      // [64][24]   = 1536 words (6 KB)
    float* Pr = lds;                                // [8][32][25] reduction (after K-loop)

    const int tok  = tid & 15;
    const int ksub = tid >> 4;                      // 0..15
    const int kk   = ksub << 2;                     // k base within 64-chunk
    const int rot  = ksub & 3;                      // bank-phase rotation

    float acc0[NL], acc1[NL];
    #pragma unroll
    for (int l = 0; l < NL; ++l) { acc0[l] = 0.f; acc1[l] = 0.f; }

    const float* tfb = tf + (size_t)(b*NS)*NH;

    // A-stage addressing (fixed per thread)
    const int rowA0 = tid >> 4,            c4A0 = tid & 15;
    const int rowA1 = (tid + 256) >> 4,    c4A1 = tid & 15;   // (tid+256)&15 == tid&15
    int trow0 = tile + rowA0 + 1; if (trow0 > 255) trow0 = 255;
    int trow1 = tile + rowA1 + 1; if (trow1 > 255) trow1 = 255;
    const float* srcA0 = tfb + (size_t)trow0*NH + (c4A0 << 2);
    const float* srcA1 = tfb + (size_t)trow1*NH + (c4A1 << 2);

    float4 pa0, pa1, pw0, pw1;
    // ---- prologue: load + commit chunk 0 ----
    pa0 = *(const float4*)(srcA0);
    pa1 = *(const float4*)(srcA1);
    {
        const float4* wsrc = (const float4*)(W);
        pw0 = wsrc[tid];
        if (tid < 128) pw1 = wsrc[tid + 256];
    }
    {
        float* d0 = As + rowA0*ASTR + (c4A0 << 2);
        d0[0]=pa0.x; d0[1]=pa0.y; d0[2]=pa0.z; d0[3]=pa0.w;
        float* d1 = As + rowA1*ASTR + (c4A1 << 2);
        d1[0]=pa1.x; d1[1]=pa1.y; d1[2]=pa1.z; d1[3]=pa1.w;
        ((float4*)Ws)[tid] = pw0;
        if (tid < 128) ((float4*)Ws)[tid + 256] = pw1;
    }
    __syncthreads();

    for (int kc0 = 0; kc0 < NH; kc0 += 64) {
        const bool more = (kc0 + 64 < NH);
        if (more) {   // issue next chunk's loads now; wait lands after compute
            pa0 = *(const float4*)(srcA0 + kc0 + 64);
            pa1 = *(const float4*)(srcA1 + kc0 + 64);
            const float4* wsrc = (const float4*)(W + (size_t)(kc0 + 64)*NL);
            pw0 = wsrc[tid];
            if (tid < 128) pw1 = wsrc[tid + 256];
        }

        const float* A0 = As + tok*ASTR + kk;
        const float* A1 = A0 + 16*ASTR;
        const float* Wr = Ws + kk*NL;
        #pragma unroll
        for (int s = 0; s < 4; ++s) {
            const int j = (s + rot) & 3;            // rotated row order (bank phase)
            float a0 = A0[j];
            float a1 = A1[j];
            const float4* w4 = (const float4*)(Wr + j*NL);
            float wv[NL];
            #pragma unroll
            for (int i = 0; i < 6; ++i) {           // 6 broadcast ds_read_b128
                float4 w = w4[i];
                wv[4*i+0] = w.x; wv[4*i+1] = w.y; wv[4*i+2] = w.z; wv[4*i+3] = w.w;
            }
            #pragma unroll
            for (int l = 0; l < NL; ++l) {
                acc0[l] = fmaf(a0, wv[l], acc0[l]);
                acc1[l] = fmaf(a1, wv[l], acc1[l]);
            }
        }
        __syncthreads();                            // all reads of this chunk done

        if (more) {                                 // commit prefetched chunk to LDS
            float* d0 = As + rowA0*ASTR + (c4A0 << 2);
            d0[0]=pa0.x; d0[1]=pa0.y; d0[2]=pa0.z; d0[3]=pa0.w;
            float* d1 = As + rowA1*ASTR + (c4A1 << 2);
            d1[0]=pa1.x; d1[1]=pa1.y; d1[2]=pa1.z; d1[3]=pa1.w;
            ((float4*)Ws)[tid] = pw0;
            if (tid < 128) ((float4*)Ws)[tid + 256] = pw1;
            __syncthreads();
        }
    }

    // ---- fold 16 ksub partials -> 8 (ksub>=8 publish, ksub<8 add), then final ----
    if (ksub >= 8) {
        float* p = Pr + ((ksub-8)*32 + tok)*25;
        float* q = p + 16*25;
        #pragma unroll
        for (int l = 0; l < NL; ++l) { p[l] = acc0[l]; q[l] = acc1[l]; }
    }
    __syncthreads();
    if (ksub < 8) {
        const float* p = Pr + (ksub*32 + tok)*25;
        const float* q = p + 16*25;
        #pragma unroll
        for (int l = 0; l < NL; ++l) { acc0[l] += p[l]; acc1[l] += q[l]; }
    }
    __syncthreads();
    if (ksub < 8) {
        float* p = Pr + (ksub*32 + tok)*25;
        float* q = p + 16*25;
        #pragma unroll
        for (int l = 0; l < NL; ++l) { p[l] = acc0[l]; q[l] = acc1[l]; }
    }
    __syncthreads();

    const int* tm = tlm + b*NS + tile;
    float* Eb = E + (size_t)(b*NS + tile)*NL;
    #pragma unroll
    for (int i = 0; i < 3; ++i) {
        int o = tid + (i << 8);                     // 0..767 (32 tok x 24 lab)
        int t = o / NL, l = o % NL;
        if (tm[t]) {
            float s = 0.f;
            #pragma unroll
            for (int ks = 0; ks < 8; ++ks)          // fixed ascending order: deterministic
                s += Pr[(ks*32 + t)*25 + l];
            float x = s + bias[l];
            Eb[t*NL + l] = 1.0f/(1.0f + expf(-x));
        }
    }
}

// ---------------- Kernel B: masked Viterbi decode, one block (256 thr) per batch ----
// Forward broadcast via 24 independent ds_bpermute (register pull through the LDS
// crossbar): one LDS-network latency per step instead of ds_write+waitcnt+ds_read.
// Values are bit-exact pass-through; adds and max tree unchanged.
__global__ __launch_bounds__(256) void ner_viterbi(
    const float* __restrict__ E, const int* __restrict__ tlm,
    const float* __restrict__ trans, const float* __restrict__ st,
    const float* __restrict__ en, int* __restrict__ out)
{
    const int tid = threadIdx.x;
    const int b   = blockIdx.x;
    const int bS  = b*NS;

    __shared__ float Esh[NS*NL];            // preloaded emissions (24.5 KB)
    __shared__ float scl[NS*NL];            // per-step score vectors (24.5 KB)
    __shared__ float Tt[NL*NL];             // Tt[c*24+p] = T[p][c]
    __shared__ float fin[NL];
    __shared__ unsigned char tr_s[NL][NS];  // trace[hypothesis][t]
    __shared__ int chosen[12];
    __shared__ int nsh, ltag;

    {
        const float4* src = (const float4*)(E + (size_t)bS*NL);
        float4* dst = (float4*)Esh;
        #pragma unroll
        for (int j = 0; j < 6; ++j) dst[tid + (j << 8)] = src[tid + (j << 8)];
    }
    for (int i = tid; i < NL*NL; i += 256) {
        int c = i / NL, p = i % NL;
        Tt[i] = trans[p*NL + c];
    }
    if (tid < 64) {   // n = lengths[b]-2 (contiguous prefix mask)
        int a = tlm[bS+tid] + tlm[bS+tid+64] + tlm[bS+tid+128] + tlm[bS+tid+192];
        #pragma unroll
        for (int off = 32; off > 0; off >>= 1) a += __shfl_down(a, off, 64);
        if (tid == 0) nsh = a;
    }
    __syncthreads();
    const int n = nsh;   // n >= 1 always

    // ---- forward: lanes 0..23 of wave 0, lane = curr tag ----
    if (tid < 24) {
        const int c = tid;
        float Tc[24];
        #pragma unroll
        for (int p = 0; p < 24; ++p) Tc[p] = trans[p*NL + c];

        auto bp = [](int idx4, float v) {   // pull lane (idx4/4)'s v — bit-exact
            return __int_as_float(__builtin_amdgcn_ds_bpermute(idx4, __float_as_int(v)));
        };

        float sv = st[c] + Esh[c];
        scl[c] = sv;                         // t=0 score vector (for backtrack)

        auto step = [&](int t, float em) {
            float scr[24];
            #pragma unroll
            for (int p = 0; p < 24; ++p) scr[p] = bp(p << 2, sv);   // 24 indep bpermutes
            float cand[24];
            #pragma unroll
            for (int p = 0; p < 24; ++p) cand[p] = scr[p] + Tc[p];  // bitwise as before
            float m0 = fmaxf(fmaxf(cand[0],  cand[1]),  cand[2]);
            float m1 = fmaxf(fmaxf(cand[3],  cand[4]),  cand[5]);
            float m2 = fmaxf(fmaxf(cand[6],  cand[7]),  cand[8]);
            float m3 = fmaxf(fmaxf(cand[9],  cand[10]), cand[11]);
            float m4 = fmaxf(fmaxf(cand[12], cand[13]), cand[14]);
            float m5 = fmaxf(fmaxf(cand[15], cand[16]), cand[17]);
            float m6 = fmaxf(fmaxf(cand[18], cand[19]), cand[20]);
            float m7 = fmaxf(fmaxf(cand[21], cand[22]), cand[23]);
            float q0 = fmaxf(fmaxf(m0, m1), m2);
            float q1 = fmaxf(fmaxf(m3, m4), m5);
            float q2 = fmaxf(m6, m7);
            float best = fmaxf(fmaxf(q0, q1), q2);
            sv = best + em;
            scl[t*NL + c] = sv;              // off critical path (backtrack input)
        };

        int t = 1;
        for (; t + 8 <= n; t += 8) {
            float em[8];
            const float* eb = Esh + t*NL + c;
            #pragma unroll
            for (int j = 0; j < 8; ++j) em[j] = eb[j*NL];   // 8 indep ds_read, imm offs
            #pragma unroll
            for (int j = 0; j < 8; ++j) step(t + j, em[j]);
        }
        for (; t < n; ++t) step(t, Esh[t*NL + c]);
        fin[c] = sv + en[c];
    }
    __syncthreads();

    if (tid == 0) {   // argmax(final), first-max tie rule like jnp.argmax
        float bv = fin[0]; int bt = 0;
        #pragma unroll
        for (int cc = 1; cc < 24; ++cc) { if (fin[cc] > bv) { bv = fin[cc]; bt = cc; } }
        ltag = bt;
    }
    __syncthreads();

    // ---- backtrack: 10 windows x 24 hypotheses, recompute backpointers ----
    const int K = (n > 1) ? (n - 1 + 9) / 10 : 1;
    if (n > 1 && tid < 240) {
        const int w = tid / 24 + 1, h = tid % 24;
        int tlo = (w-1)*K; if (tlo > n-1) tlo = n-1;
        int thi = w*K;     if (thi > n-1) thi = n-1;
        int cur = h;
        for (int t = thi; t > tlo; --t) {
            const float4* sp = (const float4*)(scl + (t-1)*NL);
            const float4* up = (const float4*)(Tt  + cur*NL);
            float cand[24];
            #pragma unroll
            for (int i = 0; i < 6; ++i) {
                float4 s = sp[i], u = up[i];
                cand[4*i+0] = s.x + u.x;     // bitwise-identical to forward cand
                cand[4*i+1] = s.y + u.y;
                cand[4*i+2] = s.z + u.z;
                cand[4*i+3] = s.w + u.w;
            }
            float best = cand[0]; int arg = 0;
            #pragma unroll
            for (int p = 1; p < 24; ++p) { if (cand[p] > best) { best = cand[p]; arg = p; } }
            tr_s[h][t-1] = (unsigned char)arg;
            cur = arg;
        }
    }
    __syncthreads();

    if (tid == 0) {   // stitch windows
        int cur = ltag;
        for (int w = 10; w >= 1; --w) {
            chosen[w] = cur;
            int tlo = (w-1)*K; if (tlo > n-1) tlo = n-1;
            int thi = w*K;     if (thi > n-1) thi = n-1;
            if (thi > tlo) cur = tr_s[cur][tlo];
        }
    }
    __syncthreads();

    {   // emit path: t >= n-1 -> last_tag (identity backpointers on padding)
        const int t = tid;
        int tag;
        if (t >= n-1) tag = ltag;
        else { int w = t / K + 1; tag = tr_s[chosen[w]][t]; }
        out[bS + t] = tag;
    }
}

extern "C" void kernel_launch(void* const* d_in, const int* in_sizes, int n_in,
                              void* d_out, int out_size, void* d_ws, size_t ws_size,
                              hipStream_t stream) {
    const float* tf    = (const float*)d_in[0];
    const int*   tlm   = (const int*)  d_in[2];   // true_label_mask
    const float* W     = (const float*)d_in[3];
    const float* bias  = (const float*)d_in[4];
    const float* trans = (const float*)d_in[5];
    const float* st    = (const float*)d_in[6];
    const float* en    = (const float*)d_in[7];
    float* E = (float*)d_ws;                      // [128,256,24] fp32 = 3.1 MB

    ner_emis<<<dim3(NB*8), dim3(256), 0, stream>>>(tf, tlm, W, bias, E);
    ner_viterbi<<<dim3(NB), dim3(256), 0, stream>>>(E, tlm, trans, st, en, (int*)d_out);
}

// Round 4
// 199.913 us; speedup vs baseline: 1.2745x; 1.0110x over previous
//
#include <hip/hip_runtime.h>
#include <math.h>

#define NB 128
#define NS 256
#define NH 768
#define NL 24
#define ASTR 68   // A-tile LDS stride (words): 68%32=4 -> 2-way banks, 16B-aligned rows
#define SCLS 28   // scl row stride (words): 16B-aligned rows, col 24 = pad for garbage lanes

// ---------------- Kernel A: emissions = sigmoid(tf[b,t+1,:] @ W + b) for t < n_b ----
// Reg-staged prefetch (T14 async-split): chunk k+1's global loads are issued before
// chunk k's compute; the vmcnt wait + ds_write land after compute, between barriers.
__global__ __launch_bounds__(256) void ner_emis(
    const float* __restrict__ tf, const int* __restrict__ tlm,
    const float* __restrict__ W, const float* __restrict__ bias,
    float* __restrict__ E)
{
    const int b    = blockIdx.x >> 3;
    const int tile = (blockIdx.x & 7) << 5;         // token base of this tile
    const int tid  = threadIdx.x;
    if (tlm[b*NS + tile] == 0) return;              // prefix mask: whole tile invalid

    __shared__ float lds[8*32*25];                  // 25.6 KB union
    float* As = lds;                                // [32][ASTR] = 2176 words (8.5 KB)
    float* Ws = lds + 32*ASTR;                      // [64][24]   = 1536 words (6 KB)
    float* Pr = lds;                                // [8][32][25] reduction (after K-loop)

    const int tok  = tid & 15;
    const int ksub = tid >> 4;                      // 0..15
    const int kk   = ksub << 2;                     // k base within 64-chunk
    const int rot  = ksub & 3;                      // bank-phase rotation

    float acc0[NL], acc1[NL];
    #pragma unroll
    for (int l = 0; l < NL; ++l) { acc0[l] = 0.f; acc1[l] = 0.f; }

    const float* tfb = tf + (size_t)(b*NS)*NH;

    // A-stage addressing (fixed per thread)
    const int rowA0 = tid >> 4,            c4A0 = tid & 15;
    const int rowA1 = (tid + 256) >> 4,    c4A1 = tid & 15;   // (tid+256)&15 == tid&15
    int trow0 = tile + rowA0 + 1; if (trow0 > 255) trow0 = 255;
    int trow1 = tile + rowA1 + 1; if (trow1 > 255) trow1 = 255;
    const float* srcA0 = tfb + (size_t)trow0*NH + (c4A0 << 2);
    const float* srcA1 = tfb + (size_t)trow1*NH + (c4A1 << 2);

    float4 pa0, pa1, pw0, pw1;
    // ---- prologue: load + commit chunk 0 ----
    pa0 = *(const float4*)(srcA0);
    pa1 = *(const float4*)(srcA1);
    {
        const float4* wsrc = (const float4*)(W);
        pw0 = wsrc[tid];
        if (tid < 128) pw1 = wsrc[tid + 256];
    }
    {
        float* d0 = As + rowA0*ASTR + (c4A0 << 2);
        d0[0]=pa0.x; d0[1]=pa0.y; d0[2]=pa0.z; d0[3]=pa0.w;
        float* d1 = As + rowA1*ASTR + (c4A1 << 2);
        d1[0]=pa1.x; d1[1]=pa1.y; d1[2]=pa1.z; d1[3]=pa1.w;
        ((float4*)Ws)[tid] = pw0;
        if (tid < 128) ((float4*)Ws)[tid + 256] = pw1;
    }
    __syncthreads();

    for (int kc0 = 0; kc0 < NH; kc0 += 64) {
        const bool more = (kc0 + 64 < NH);
        if (more) {   // issue next chunk's loads now; wait lands after compute
            pa0 = *(const float4*)(srcA0 + kc0 + 64);
            pa1 = *(const float4*)(srcA1 + kc0 + 64);
            const float4* wsrc = (const float4*)(W + (size_t)(kc0 + 64)*NL);
            pw0 = wsrc[tid];
            if (tid < 128) pw1 = wsrc[tid + 256];
        }

        const float* A0 = As + tok*ASTR + kk;
        const float* A1 = A0 + 16*ASTR;
        const float* Wr = Ws + kk*NL;
        #pragma unroll
        for (int s = 0; s < 4; ++s) {
            const int j = (s + rot) & 3;            // rotated row order (bank phase)
            float a0 = A0[j];
            float a1 = A1[j];
            const float4* w4 = (const float4*)(Wr + j*NL);
            float wv[NL];
            #pragma unroll
            for (int i = 0; i < 6; ++i) {           // 6 broadcast ds_read_b128
                float4 w = w4[i];
                wv[4*i+0] = w.x; wv[4*i+1] = w.y; wv[4*i+2] = w.z; wv[4*i+3] = w.w;
            }
            #pragma unroll
            for (int l = 0; l < NL; ++l) {
                acc0[l] = fmaf(a0, wv[l], acc0[l]);
                acc1[l] = fmaf(a1, wv[l], acc1[l]);
            }
        }
        __syncthreads();                            // all reads of this chunk done

        if (more) {                                 // commit prefetched chunk to LDS
            float* d0 = As + rowA0*ASTR + (c4A0 << 2);
            d0[0]=pa0.x; d0[1]=pa0.y; d0[2]=pa0.z; d0[3]=pa0.w;
            float* d1 = As + rowA1*ASTR + (c4A1 << 2);
            d1[0]=pa1.x; d1[1]=pa1.y; d1[2]=pa1.z; d1[3]=pa1.w;
            ((float4*)Ws)[tid] = pw0;
            if (tid < 128) ((float4*)Ws)[tid + 256] = pw1;
            __syncthreads();
        }
    }

    // ---- fold 16 ksub partials -> 8 (ksub>=8 publish, ksub<8 add), then final ----
    if (ksub >= 8) {
        float* p = Pr + ((ksub-8)*32 + tok)*25;
        float* q = p + 16*25;
        #pragma unroll
        for (int l = 0; l < NL; ++l) { p[l] = acc0[l]; q[l] = acc1[l]; }
    }
    __syncthreads();
    if (ksub < 8) {
        const float* p = Pr + (ksub*32 + tok)*25;
        const float* q = p + 16*25;
        #pragma unroll
        for (int l = 0; l < NL; ++l) { acc0[l] += p[l]; acc1[l] += q[l]; }
    }
    __syncthreads();
    if (ksub < 8) {
        float* p = Pr + (ksub*32 + tok)*25;
        float* q = p + 16*25;
        #pragma unroll
        for (int l = 0; l < NL; ++l) { p[l] = acc0[l]; q[l] = acc1[l]; }
    }
    __syncthreads();

    const int* tm = tlm + b*NS + tile;
    float* Eb = E + (size_t)(b*NS + tile)*NL;
    #pragma unroll
    for (int i = 0; i < 3; ++i) {
        int o = tid + (i << 8);                     // 0..767 (32 tok x 24 lab)
        int t = o / NL, l = o % NL;
        if (tm[t]) {
            float s = 0.f;
            #pragma unroll
            for (int ks = 0; ks < 8; ++ks)          // fixed ascending order: deterministic
                s += Pr[(ks*32 + t)*25 + l];
            float x = s + bias[l];
            Eb[t*NL + l] = 1.0f/(1.0f + expf(-x));
        }
    }
}

// ---------------- Kernel B: masked Viterbi decode, one block (256 thr) per batch ----
// Forward split 2-lanes-per-tag: lane c handles prev-tags [0,12), lane c+32 handles
// [12,24) -> 12 ds_bpermute per step (halved DS-pipe time); partial maxes combined
// via v_permlane32_swap (VALU) or cross-half bpermute fallback. Max reassociation is
// bit-exact (finite floats); candidate adds and backtrack argmax order unchanged.
__global__ __launch_bounds__(256) void ner_viterbi(
    const float* __restrict__ E, const int* __restrict__ tlm,
    const float* __restrict__ trans, const float* __restrict__ st,
    const float* __restrict__ en, int* __restrict__ out)
{
    const int tid = threadIdx.x;
    const int b   = blockIdx.x;
    const int bS  = b*NS;

    __shared__ float Esh[NS*NL];            // preloaded emissions (24 KB)
    __shared__ float scl[NS*SCLS];          // per-step score vectors (28 KB)
    __shared__ float Tt[NL*NL];             // Tt[c*24+p] = T[p][c]
    __shared__ float fin[32];
    __shared__ unsigned char tr_s[NL][NS];  // trace[hypothesis][t]
    __shared__ int chosen[12];
    __shared__ int nsh, ltag;

    {
        const float4* src = (const float4*)(E + (size_t)bS*NL);
        float4* dst = (float4*)Esh;
        #pragma unroll
        for (int j = 0; j < 6; ++j) dst[tid + (j << 8)] = src[tid + (j << 8)];
    }
    for (int i = tid; i < NL*NL; i += 256) {
        int c = i / NL, p = i % NL;
        Tt[i] = trans[p*NL + c];
    }
    if (tid < 64) {   // n = lengths[b]-2 (contiguous prefix mask)
        int a = tlm[bS+tid] + tlm[bS+tid+64] + tlm[bS+tid+128] + tlm[bS+tid+192];
        #pragma unroll
        for (int off = 32; off > 0; off >>= 1) a += __shfl_down(a, off, 64);
        if (tid == 0) nsh = a;
    }
    __syncthreads();
    const int n = nsh;   // n >= 1 always

    // ---- forward: all 64 lanes of wave 0; lanes c and c+32 both own tag c ----
    if (tid < 64) {
        const int lane = tid;
        const int h    = lane >> 5;          // half: prev-tags [12h, 12h+12)
        const int c    = lane & 31;          // tag; c>=24 lanes are garbage (never sourced)
        const int cidx = (c < 24) ? c : 23;  // clamped index for global reads
        const int coff = (c < 24) ? c : 24;  // scl column (24 = pad)
        const int p0   = h * 12;

        float Tc[12];
        #pragma unroll
        for (int j = 0; j < 12; ++j) Tc[j] = trans[(p0 + j)*NL + cidx];

        int idxv[12];
        #pragma unroll
        for (int j = 0; j < 12; ++j) idxv[j] = (p0 + j) << 2;

        auto bp = [](int idx4, float v) {   // pull lane (idx4/4)'s v — bit-exact
            return __int_as_float(__builtin_amdgcn_ds_bpermute(idx4, __float_as_int(v)));
        };

        float sv = st[cidx] + Esh[cidx];     // identical in lanes c and c+32
        scl[coff] = sv;                      // t=0 score vector (for backtrack)

        auto step = [&](int t, float em) {
            float cand[12];
            #pragma unroll
            for (int j = 0; j < 12; ++j)     // 12 indep bpermutes (halved DS-pipe)
                cand[j] = bp(idxv[j], sv) + Tc[j];
            float a0 = fmaxf(fmaxf(cand[0], cand[1]),  cand[2]);
            float a1 = fmaxf(fmaxf(cand[3], cand[4]),  cand[5]);
            float a2 = fmaxf(fmaxf(cand[6], cand[7]),  cand[8]);
            float a3 = fmaxf(fmaxf(cand[9], cand[10]), cand[11]);
            float pm = fmaxf(fmaxf(a0, a1), fmaxf(a2, a3));   // partial over 12 prevs
            // combine the two halves: both lanes end with max over all 24 prevs
#if __has_builtin(__builtin_amdgcn_permlane32_swap)
            auto r = __builtin_amdgcn_permlane32_swap(
                         __float_as_int(pm), __float_as_int(pm), false, false);
            float best = fmaxf(__int_as_float(r[0]), __int_as_float(r[1]));
#else
            float best = fmaxf(pm, bp((lane ^ 32) << 2, pm));
#endif
            sv = best + em;
            scl[t*SCLS + coff] = sv;         // off critical path (backtrack input)
        };

        int t = 1;
        for (; t + 8 <= n; t += 8) {
            float em[8];
            const float* eb = Esh + t*NL + cidx;
            #pragma unroll
            for (int j = 0; j < 8; ++j) em[j] = eb[j*NL];   // 8 indep ds_read, imm offs
            #pragma unroll
            for (int j = 0; j < 8; ++j) step(t + j, em[j]);
        }
        for (; t < n; ++t) step(t, Esh[t*NL + cidx]);
        fin[c] = sv + en[cidx];              // c>=24 -> pad slots of fin[32]
    }
    __syncthreads();

    if (tid == 0) {   // argmax(final), first-max tie rule like jnp.argmax
        float bv = fin[0]; int bt = 0;
        #pragma unroll
        for (int cc = 1; cc < 24; ++cc) { if (fin[cc] > bv) { bv = fin[cc]; bt = cc; } }
        ltag = bt;
    }
    __syncthreads();

    // ---- backtrack: 10 windows x 24 hypotheses, recompute backpointers ----
    const int K = (n > 1) ? (n - 1 + 9) / 10 : 1;
    if (n > 1 && tid < 240) {
        const int w = tid / 24 + 1, h = tid % 24;
        int tlo = (w-1)*K; if (tlo > n-1) tlo = n-1;
        int thi = w*K;     if (thi > n-1) thi = n-1;
        int cur = h;
        for (int t = thi; t > tlo; --t) {
            const float4* sp = (const float4*)(scl + (t-1)*SCLS);
            const float4* up = (const float4*)(Tt  + cur*NL);
            float cand[24];
            #pragma unroll
            for (int i = 0; i < 6; ++i) {
                float4 s = sp[i], u = up[i];
                cand[4*i+0] = s.x + u.x;     // bitwise-identical to forward cand
                cand[4*i+1] = s.y + u.y;
                cand[4*i+2] = s.z + u.z;
                cand[4*i+3] = s.w + u.w;
            }
            float best = cand[0]; int arg = 0;
            #pragma unroll
            for (int p = 1; p < 24; ++p) { if (cand[p] > best) { best = cand[p]; arg = p; } }
            tr_s[h][t-1] = (unsigned char)arg;
            cur = arg;
        }
    }
    __syncthreads();

    if (tid == 0) {   // stitch windows
        int cur = ltag;
        for (int w = 10; w >= 1; --w) {
            chosen[w] = cur;
            int tlo = (w-1)*K; if (tlo > n-1) tlo = n-1;
            int thi = w*K;     if (thi > n-1) thi = n-1;
            if (thi > tlo) cur = tr_s[cur][tlo];
        }
    }
    __syncthreads();

    {   // emit path: t >= n-1 -> last_tag (identity backpointers on padding)
        const int t = tid;
        int tag;
        if (t >= n-1) tag = ltag;
        else { int w = t / K + 1; tag = tr_s[chosen[w]][t]; }
        out[bS + t] = tag;
    }
}

extern "C" void kernel_launch(void* const* d_in, const int* in_sizes, int n_in,
                              void* d_out, int out_size, void* d_ws, size_t ws_size,
                              hipStream_t stream) {
    const float* tf    = (const float*)d_in[0];
    const int*   tlm   = (const int*)  d_in[2];   // true_label_mask
    const float* W     = (const float*)d_in[3];
    const float* bias  = (const float*)d_in[4];
    const float* trans = (const float*)d_in[5];
    const float* st    = (const float*)d_in[6];
    const float* en    = (const float*)d_in[7];
    float* E = (float*)d_ws;                      // [128,256,24] fp32 = 3.1 MB

    ner_emis<<<dim3(NB*8), dim3(256), 0, stream>>>(tf, tlm, W, bias, E);
    ner_viterbi<<<dim3(NB), dim3(256), 0, stream>>>(E, tlm, trans, st, en, (int*)d_out);
}